// Round 3
// baseline (592.846 us; speedup 1.0000x reference)
//
#include <hip/hip_runtime.h>
#include <cstdint>
#include <cstddef>

#define N_TOT 16384
#define DIM 512
#define EPS 1e-8f

typedef __attribute__((ext_vector_type(8))) short short8;
typedef __attribute__((ext_vector_type(16))) float f32x16;

// round-to-nearest-even fp32 -> bf16 (inputs are finite; no NaN path needed)
static __device__ __forceinline__ short f2bf(float f) {
  union { float f; unsigned u; } un; un.f = f;
  unsigned r = un.u + 0x7FFFu + ((un.u >> 16) & 1u);
  return (short)(r >> 16);
}

// ---------------------------------------------------------------------------
// ws layout (bytes):
//   [0,          16777216)  imgF  bf16 frag-ordered
//   [16777216,   33554432)  txtF  bf16 frag-ordered
//   [33554432,   34078720)  partials float2 [dir(2)][split(2)][16384]
//   [34078720,   34144256)  diag  float [16384]
// Frag order: chunk = row32*32 + k16; within chunk lane l (0..63), elem e:
//   row = row32*32 + (l&31), k = k16*16 + (l>>5)*8 + e
// This matches the mfma_f32_32x32x16_bf16 A/B fragment (lane -> row l&31,
// k = (l>>5)*8..+8), so frag reads are 16B-linear per lane.
// ---------------------------------------------------------------------------

__global__ __launch_bounds__(256) void convert_kernel(
    const float* __restrict__ img, const float* __restrict__ txt,
    short* __restrict__ imgF, short* __restrict__ txtF) {
  const float* src = blockIdx.y ? txt : img;
  short* dst = blockIdx.y ? txtF : imgF;
  int tm = blockIdx.x * 256 + threadIdx.x;      // 0 .. 1048575
  int chunk = tm >> 6, l = tm & 63;
  int row32 = chunk >> 5, k16 = chunk & 31;
  int row = row32 * 32 + (l & 31);
  int kb = k16 * 16 + ((l >> 5) << 3);
  const float* p = src + (size_t)row * DIM + kb;
  short8 v;
#pragma unroll
  for (int e = 0; e < 8; ++e) v[e] = f2bf(p[e]);
  *reinterpret_cast<short8*>(dst + (size_t)tm * 8) = v;   // fully coalesced 16B
}

// ---------------------------------------------------------------------------
// Fused GEMM + online row-LSE. 8 waves/block, wave owns 32 rows (A in regs),
// BM=256, BN=64 per col-tile, BK=64 per stage (4 x K16), B dbuf in LDS.
// grid = (split 2, rowblock 64, dir 2) = 256 blocks = 1/CU.
// ---------------------------------------------------------------------------
__global__ __launch_bounds__(512, 2) void lse_gemm_kernel(
    const short* __restrict__ imgF, const short* __restrict__ txtF,
    const float* __restrict__ scale_p, float2* __restrict__ partials) {
  const int split = blockIdx.x;           // 0..1  : column half
  const int rb    = blockIdx.y;           // 0..63 : 256-row block
  const int dir   = blockIdx.z;           // 0: rows=img, 1: rows=txt
  const short* __restrict__ AF = dir ? txtF : imgF;
  const short* __restrict__ BF = dir ? imgF : txtF;
  const int wid = threadIdx.x >> 6;
  const int l   = threadIdx.x & 63;
  const float scale = *scale_p;

  __shared__ short Bs[2][8][512];         // [buf][chunk: c32l*4+kk][64 lanes * 8]

  // --- A: this wave's 32 rows x 512 K, in registers (32 frags) ---
  const int row32g = rb * 8 + wid;
  short8 afrag[32];
  {
    const short* ap = AF + (size_t)row32g * 32 * 512 + l * 8;
#pragma unroll
    for (int k = 0; k < 32; ++k)
      afrag[k] = *reinterpret_cast<const short8*>(ap + k * 512);
  }

  // per-lane running LSE stats for this lane's 16 (row, own-columns) slots
  float m_l[16], s_l[16];
#pragma unroll
  for (int r = 0; r < 16; ++r) { m_l[r] = -__builtin_inff(); s_l[r] = 0.f; }

  const int c32base = split * 256;        // col32 units (8192 cols per split)
  const int myc = wid >> 2, myk = wid & 3;

  // prologue: stage (ct=0, ks=0) into buf 0
  {
    int chunk = (c32base + myc) * 32 + myk;
    const short* g = BF + (size_t)chunk * 512 + l * 8;
    __builtin_amdgcn_global_load_lds(
        (const __attribute__((address_space(1))) unsigned int*)g,
        (__attribute__((address_space(3))) unsigned int*)(&Bs[0][wid][0]), 16, 0, 0);
  }
  __syncthreads();

  const int NCT = (N_TOT / 2) / 64;       // 128 col tiles per block
  for (int ct = 0; ct < NCT; ++ct) {
    f32x16 acc0, acc1;
#pragma unroll
    for (int r = 0; r < 16; ++r) { acc0[r] = 0.f; acc1[r] = 0.f; }

#pragma unroll
    for (int ks = 0; ks < 8; ++ks) {
      const int cur = ks & 1;
      // prefetch next stage into the other buffer (uniform condition)
      int nct = ct, nks = ks + 1;
      if (nks == 8) { nks = 0; ++nct; }
      if (nct < NCT) {
        int chunk = (c32base + nct * 2 + myc) * 32 + (nks * 4 + myk);
        const short* g = BF + (size_t)chunk * 512 + l * 8;
        __builtin_amdgcn_global_load_lds(
            (const __attribute__((address_space(1))) unsigned int*)g,
            (__attribute__((address_space(3))) unsigned int*)(&Bs[cur ^ 1][wid][0]), 16, 0, 0);
      }
#pragma unroll
      for (int kk = 0; kk < 4; ++kk) {
        short8 b0 = *reinterpret_cast<const short8*>(&Bs[cur][kk][l * 8]);
        short8 b1 = *reinterpret_cast<const short8*>(&Bs[cur][4 + kk][l * 8]);
        acc0 = __builtin_amdgcn_mfma_f32_32x32x16_bf16(afrag[ks * 4 + kk], b0, acc0, 0, 0, 0);
        acc1 = __builtin_amdgcn_mfma_f32_32x32x16_bf16(afrag[ks * 4 + kk], b1, acc1, 0, 0, 0);
      }
      __syncthreads();   // drains vmcnt (prefetch) + lgkm; protects buf reuse
    }

    // online LSE update; C layout: col = l&31 (+n*32), row = (r&3)+8*(r>>2)+4*(l>>5)
#pragma unroll
    for (int r = 0; r < 16; ++r) {
      float v0 = acc0[r] * scale, v1 = acc1[r] * scale;
      float mnew = fmaxf(m_l[r], fmaxf(v0, v1));
      s_l[r] = s_l[r] * __expf(m_l[r] - mnew) + __expf(v0 - mnew) + __expf(v1 - mnew);
      m_l[r] = mnew;
    }
  }

  // merge (m,s) across the 32 lanes of each half-wave (butterfly, deterministic)
#pragma unroll
  for (int r = 0; r < 16; ++r) {
    float m = m_l[r], s = s_l[r];
#pragma unroll
    for (int off = 1; off < 32; off <<= 1) {
      float mo = __shfl_xor(m, off, 64);
      float so = __shfl_xor(s, off, 64);
      float mn = fmaxf(m, mo);
      s = s * __expf(m - mn) + so * __expf(mo - mn);
      m = mn;
    }
    m_l[r] = m; s_l[r] = s;
  }
  if ((l & 31) == 0) {
    int rbase = rb * 256 + wid * 32 + ((l >> 5) << 2);
#pragma unroll
    for (int r = 0; r < 16; ++r) {
      int row = rbase + (r & 3) + ((r >> 2) << 3);
      float2 p; p.x = m_l[r]; p.y = s_l[r];
      partials[(size_t)(dir * 2 + split) * N_TOT + row] = p;
    }
  }
}

// exact fp32 diagonal: one wave per row
__global__ __launch_bounds__(256) void diag_kernel(
    const float* __restrict__ img, const float* __restrict__ txt,
    float* __restrict__ diag) {
  int wid = threadIdx.x >> 6, l = threadIdx.x & 63;
  int row = blockIdx.x * 4 + wid;
  const float4* a = reinterpret_cast<const float4*>(img + (size_t)row * DIM) + l * 2;
  const float4* b = reinterpret_cast<const float4*>(txt + (size_t)row * DIM) + l * 2;
  float s = 0.f;
#pragma unroll
  for (int j = 0; j < 2; ++j) {
    float4 x = a[j], y = b[j];
    s += x.x * y.x + x.y * y.y + x.z * y.z + x.w * y.w;
  }
#pragma unroll
  for (int off = 32; off > 0; off >>= 1) s += __shfl_down(s, off, 64);
  if (l == 0) diag[row] = s;
}

// merge split partials, add diagonal term, single-block deterministic reduce
__global__ __launch_bounds__(256) void final_kernel(
    const float2* __restrict__ partials, const float* __restrict__ diag,
    const float* __restrict__ scale_p, float* __restrict__ out) {
  int t = threadIdx.x;
  float sden = 0.f, sdiag = 0.f;
  for (int i = t; i < N_TOT; i += 256) {
#pragma unroll
    for (int d = 0; d < 2; ++d) {
      float2 p0 = partials[(size_t)(d * 2 + 0) * N_TOT + i];
      float2 p1 = partials[(size_t)(d * 2 + 1) * N_TOT + i];
      float m = fmaxf(p0.x, p1.x);
      float s = p0.y * __expf(p0.x - m) + p1.y * __expf(p1.x - m);
      sden += m + __logf(s + EPS * __expf(-m));
    }
    sdiag += diag[i];
  }
  __shared__ float rA[256], rB[256];
  rA[t] = sden; rB[t] = sdiag;
  __syncthreads();
  for (int s2 = 128; s2 > 0; s2 >>= 1) {
    if (t < s2) { rA[t] += rA[t + s2]; rB[t] += rB[t + s2]; }
    __syncthreads();
  }
  if (t == 0)
    out[0] = 0.5f * rA[0] / (float)N_TOT - (*scale_p) * rB[0] / (float)N_TOT;
}

extern "C" void kernel_launch(void* const* d_in, const int* in_sizes, int n_in,
                              void* d_out, int out_size, void* d_ws, size_t ws_size,
                              hipStream_t stream) {
  const float* img     = (const float*)d_in[0];
  const float* txt     = (const float*)d_in[1];
  const float* scale_p = (const float*)d_in[2];
  float* out = (float*)d_out;
  char* ws = (char*)d_ws;   // needs ~34.2 MB
  short*  imgF     = (short*)(ws);
  short*  txtF     = (short*)(ws + (size_t)16777216);
  float2* partials = (float2*)(ws + (size_t)33554432);
  float*  diag     = (float*)(ws + (size_t)34078720);

  convert_kernel<<<dim3(4096, 2, 1), 256, 0, stream>>>(img, txt, imgF, txtF);
  lse_gemm_kernel<<<dim3(2, 64, 2), 512, 0, stream>>>(imgF, txtF, scale_p, partials);
  diag_kernel<<<dim3(4096, 1, 1), 256, 0, stream>>>(img, txt, diag);
  final_kernel<<<dim3(1, 1, 1), 256, 0, stream>>>(partials, diag, scale_p, out);
}

// Round 4
// 325.931 us; speedup vs baseline: 1.8189x; 1.8189x over previous
//
#include <hip/hip_runtime.h>
#include <cstdint>
#include <cstddef>

#define N_TOT 16384
#define DIM 512
#define EPS 1e-8f
#define LOG2E 1.44269504088896340736f

typedef __attribute__((ext_vector_type(8))) short short8;
typedef __attribute__((ext_vector_type(16))) float f32x16;

// round-to-nearest-even fp32 -> bf16
static __device__ __forceinline__ short f2bf(float f) {
  union { float f; unsigned u; } un; un.f = f;
  unsigned r = un.u + 0x7FFFu + ((un.u >> 16) & 1u);
  return (short)(r >> 16);
}

// ---------------------------------------------------------------------------
// ws layout (bytes):
//   [0,        16777216)  imgF  bf16 frag-ordered
//   [16777216, 33554432)  txtF  bf16 frag-ordered
//   [33554432, 37748736)  colpart float [64 rb][16384]
//   [37748736, 38010880)  rowpart float [4 split][16384]
//   [38010880, 38076416)  colLSE  float [16384]
//   [38076416, 38141952)  diag    float [16384]
// Frag order: chunk = grp32*32 + k16; lane l, elem e:
//   row = grp32*32 + (l&31), k = k16*16 + (l>>5)*8 + e  (A and B use the SAME
//   (lane,e)->k map, so the MFMA dot is correct independent of HW k-order).
// ---------------------------------------------------------------------------

__global__ __launch_bounds__(256) void convert_kernel(
    const float* __restrict__ img, const float* __restrict__ txt,
    short* __restrict__ imgF, short* __restrict__ txtF) {
  const float* src = blockIdx.y ? txt : img;
  short* dst = blockIdx.y ? txtF : imgF;
  int tm = blockIdx.x * 256 + threadIdx.x;
  int chunk = tm >> 6, l = tm & 63;
  int grp32 = chunk >> 5, k16 = chunk & 31;
  int row = grp32 * 32 + (l & 31);
  int kb = k16 * 16 + ((l >> 5) << 3);
  const float* p = src + (size_t)row * DIM + kb;
  short8 v;
#pragma unroll
  for (int e = 0; e < 8; ++e) v[e] = f2bf(p[e]);
  *reinterpret_cast<short8*>(dst + (size_t)tm * 8) = v;
}

// ---------------------------------------------------------------------------
// Single-pass fused GEMM + row-sumexp + col-sumexp (no online max; |logit|<2).
// 8 waves, wave owns 32 rows (A in regs, 32 frags). B: full 32-col x K512
// panel in LDS, double-buffered (2 x 32KB). One barrier per panel.
// grid = (split 4, rb 64) = 256 blocks = 1/CU.
// ---------------------------------------------------------------------------
__global__ __launch_bounds__(512, 2) void fused_lse_kernel(
    const short* __restrict__ imgF, const short* __restrict__ txtF,
    const float* __restrict__ scale_p,
    float* __restrict__ rowpart,   // [4][16384]
    float* __restrict__ colpart) { // [64][16384]
  const int split = blockIdx.x;          // 0..3 : 4096-col slice
  const int rb    = blockIdx.y;          // 0..63: 256-row block
  const int wid = threadIdx.x >> 6;
  const int l   = threadIdx.x & 63;
  const float cexp = (*scale_p) * LOG2E; // exp(scale*x) = exp2(x*cexp)

  __shared__ short Bs[2][32][512];       // 2 x 32KB B panel (32 cols x 512 K)
  __shared__ float colLDS[2][8][32];     // parity-dbuf cross-wave col merge

  // A: this wave's 32 rows x 512 K in registers (32 frags = 128 VGPR)
  const int row32g = rb * 8 + wid;
  short8 afrag[32];
  {
    const short* ap = imgF + (size_t)row32g * (32 * 512) + l * 8;
#pragma unroll
    for (int k = 0; k < 32; ++k)
      afrag[k] = *reinterpret_cast<const short8*>(ap + k * 512);
  }

  float rowsum[16];
#pragma unroll
  for (int r = 0; r < 16; ++r) rowsum[r] = 0.f;

  const int g0 = split * 128;            // col32-group base

  // prologue: stage panel ct=0 into buf 0 (wave stages k16 = wid*4 .. +4)
  {
    const short* g = txtF + ((size_t)g0 * 32 + wid * 4) * 512 + l * 8;
#pragma unroll
    for (int j = 0; j < 4; ++j)
      __builtin_amdgcn_global_load_lds(
          (const __attribute__((address_space(1))) unsigned int*)(g + j * 512),
          (__attribute__((address_space(3))) unsigned int*)(&Bs[0][wid * 4 + j][0]),
          16, 0, 0);
  }
  __syncthreads();

  const int NCT = 128;                   // 32-col panels per block
  for (int ct = 0; ct < NCT; ++ct) {
    const int cur = ct & 1;
    // stage next panel into other buffer; latency hidden under 32 MFMAs
    if (ct + 1 < NCT) {
      const short* g = txtF + ((size_t)(g0 + ct + 1) * 32 + wid * 4) * 512 + l * 8;
#pragma unroll
      for (int j = 0; j < 4; ++j)
        __builtin_amdgcn_global_load_lds(
            (const __attribute__((address_space(1))) unsigned int*)(g + j * 512),
            (__attribute__((address_space(3))) unsigned int*)(&Bs[cur ^ 1][wid * 4 + j][0]),
            16, 0, 0);
    }
    f32x16 accA, accB;                   // 2 chains: break MFMA dep latency
#pragma unroll
    for (int r = 0; r < 16; ++r) { accA[r] = 0.f; accB[r] = 0.f; }
#pragma unroll
    for (int k16 = 0; k16 < 32; k16 += 2) {
      short8 b0 = *reinterpret_cast<const short8*>(&Bs[cur][k16][l * 8]);
      short8 b1 = *reinterpret_cast<const short8*>(&Bs[cur][k16 + 1][l * 8]);
      accA = __builtin_amdgcn_mfma_f32_32x32x16_bf16(afrag[k16], b0, accA, 0, 0, 0);
      accB = __builtin_amdgcn_mfma_f32_32x32x16_bf16(afrag[k16 + 1], b1, accB, 0, 0, 0);
    }
    // tail: one exp feeds BOTH row- and col-sums (no max needed: |arg|<~2)
    float colp = 0.f;
#pragma unroll
    for (int r = 0; r < 16; ++r) {
      float e = exp2f((accA[r] + accB[r]) * cexp);
      rowsum[r] += e;
      colp += e;
    }
    colp += __shfl_xor(colp, 32, 64);    // merge the two row-halves per col
    if (l < 32) colLDS[cur][wid][l] = colp;
    __syncthreads();                     // also drains next-panel vmcnt
    if (threadIdx.x < 32) {              // cross-wave col merge + flush
      float s = 0.f;
#pragma unroll
      for (int w = 0; w < 8; ++w) s += colLDS[cur][w][threadIdx.x];
      colpart[(size_t)rb * N_TOT + (size_t)(g0 + ct) * 32 + threadIdx.x] = s;
    }
  }

  // row sums: butterfly over the 32 col-lanes (sum only, deterministic)
#pragma unroll
  for (int r = 0; r < 16; ++r) {
    float s = rowsum[r];
#pragma unroll
    for (int off = 1; off < 32; off <<= 1) s += __shfl_xor(s, off, 64);
    rowsum[r] = s;
  }
  if ((l & 31) == 0) {
    int rbase = rb * 256 + wid * 32 + ((l >> 5) << 2);
#pragma unroll
    for (int r = 0; r < 16; ++r) {
      int row = rbase + (r & 3) + ((r >> 2) << 3);
      rowpart[(size_t)split * N_TOT + row] = rowsum[r];
    }
  }
}

// exact fp32 diagonal: one wave per row
__global__ __launch_bounds__(256) void diag_kernel(
    const float* __restrict__ img, const float* __restrict__ txt,
    float* __restrict__ diag) {
  int wid = threadIdx.x >> 6, l = threadIdx.x & 63;
  int row = blockIdx.x * 4 + wid;
  const float4* a = reinterpret_cast<const float4*>(img + (size_t)row * DIM) + l * 2;
  const float4* b = reinterpret_cast<const float4*>(txt + (size_t)row * DIM) + l * 2;
  float s = 0.f;
#pragma unroll
  for (int j = 0; j < 2; ++j) {
    float4 x = a[j], y = b[j];
    s += x.x * y.x + x.y * y.y + x.z * y.z + x.w * y.w;
  }
#pragma unroll
  for (int off = 32; off > 0; off >>= 1) s += __shfl_down(s, off, 64);
  if (l == 0) diag[row] = s;
}

// per-column: sum 64 rb partials, take log
__global__ __launch_bounds__(256) void colreduce_kernel(
    const float* __restrict__ colpart, float* __restrict__ colLSE) {
  int col = blockIdx.x * 256 + threadIdx.x;
  float s = 0.f;
#pragma unroll 8
  for (int g = 0; g < 64; ++g) s += colpart[(size_t)g * N_TOT + col];
  colLSE[col] = __logf(s + EPS);
}

// merge row partials, add col LSEs and diagonal, single-block reduce
__global__ __launch_bounds__(256) void final_kernel(
    const float* __restrict__ rowpart, const float* __restrict__ colLSE,
    const float* __restrict__ diag, const float* __restrict__ scale_p,
    float* __restrict__ out) {
  int t = threadIdx.x;
  float sden = 0.f, sdiag = 0.f;
  for (int i = t; i < N_TOT; i += 256) {
    float rs = rowpart[i] + rowpart[N_TOT + i] + rowpart[2 * N_TOT + i] + rowpart[3 * N_TOT + i];
    sden += __logf(rs + EPS) + colLSE[i];
    sdiag += diag[i];
  }
  __shared__ float rA[256], rB[256];
  rA[t] = sden; rB[t] = sdiag;
  __syncthreads();
  for (int s2 = 128; s2 > 0; s2 >>= 1) {
    if (t < s2) { rA[t] += rA[t + s2]; rB[t] += rB[t + s2]; }
    __syncthreads();
  }
  if (t == 0)
    out[0] = 0.5f * rA[0] / (float)N_TOT - (*scale_p) * rB[0] / (float)N_TOT;
}

extern "C" void kernel_launch(void* const* d_in, const int* in_sizes, int n_in,
                              void* d_out, int out_size, void* d_ws, size_t ws_size,
                              hipStream_t stream) {
  const float* img     = (const float*)d_in[0];
  const float* txt     = (const float*)d_in[1];
  const float* scale_p = (const float*)d_in[2];
  float* out = (float*)d_out;
  char* ws = (char*)d_ws;   // needs ~36.4 MB
  short* imgF    = (short*)(ws);
  short* txtF    = (short*)(ws + (size_t)16777216);
  float* colpart = (float*)(ws + (size_t)33554432);
  float* rowpart = (float*)(ws + (size_t)37748736);
  float* colLSE  = (float*)(ws + (size_t)38010880);
  float* diag    = (float*)(ws + (size_t)38076416);

  convert_kernel<<<dim3(4096, 2, 1), 256, 0, stream>>>(img, txt, imgF, txtF);
  fused_lse_kernel<<<dim3(4, 64, 1), 512, 0, stream>>>(imgF, txtF, scale_p, rowpart, colpart);
  diag_kernel<<<dim3(4096, 1, 1), 256, 0, stream>>>(img, txt, diag);
  colreduce_kernel<<<dim3(64, 1, 1), 256, 0, stream>>>(colpart, colLSE);
  final_kernel<<<dim3(1, 1, 1), 256, 0, stream>>>(rowpart, colLSE, diag, scale_p, out);
}

// Round 5
// 219.614 us; speedup vs baseline: 2.6995x; 1.4841x over previous
//
#include <hip/hip_runtime.h>
#include <cstdint>
#include <cstddef>

#define N_TOT 16384
#define DIM 512
#define EPS 1e-8f
#define LOG2E 1.44269504088896340736f
#define SCALE1 0x7F7F7F7Fu   // E8M0 = 127 -> 2^0 in every byte

typedef __attribute__((ext_vector_type(8))) int int8v;
typedef __attribute__((ext_vector_type(16))) float f32x16;

union FragU { int4 q[2]; int8v v; };

// ---------------------------------------------------------------------------
// fp8 frag-linear layout (per matrix, 8 MB):
//   chunk = grp32*8 + k64   (grp32: 32-row group 0..511, k64: 0..7)
//   chunk is 2048 B = two 1024 B halves h=0,1; lane l, elem j(0..15):
//     byte = chunk*2048 + h*1024 + l*16 + j
//     row  = grp32*32 + (l&31),  k = k64*64 + (l>>5)*32 + h*16 + j
//   A and B use the SAME (lane,elem)->k bijection => MFMA dot correct
//   independent of HW k-order; uniform MX scales make block-mapping moot.
// ws layout (bytes):
//   [0,        8388608)   imgF fp8
//   [8388608,  16777216)  txtF fp8
//   [16777216, 18874368)  colpart float [32 rb][16384]
//   [18874368, 19398656)  rowpart float [8 split][16384]
//   [19398656, 19464192)  colLSE float [16384]
//   [19464192, 19529728)  diag   float [16384]
// ---------------------------------------------------------------------------

__global__ __launch_bounds__(256) void convert_kernel(
    const float* __restrict__ img, const float* __restrict__ txt,
    const float* __restrict__ scale_p,
    char* __restrict__ imgF, char* __restrict__ txtF) {
  const float fac = sqrtf((*scale_p) * LOG2E);  // exp(scale*S) = exp2(dot of scaled inputs)
  const float* src = blockIdx.y ? txt : img;
  char* dst = blockIdx.y ? txtF : imgF;
  int tm = blockIdx.x * 256 + threadIdx.x;      // 0..524287
  int c = tm >> 7;                               // chunk 0..4095
  int h = (tm >> 6) & 1;
  int l = tm & 63;
  int grp32 = c >> 3, k64 = c & 7;
  int row = grp32 * 32 + (l & 31);
  int kb = k64 * 64 + ((l >> 5) << 5) + h * 16;
  const float* p = src + (size_t)row * DIM + kb;
  float f[16];
#pragma unroll
  for (int e = 0; e < 16; ++e) f[e] = p[e] * fac;
  int4 w;
  int w0 = 0, w1 = 0, w2 = 0, w3 = 0;
  w0 = __builtin_amdgcn_cvt_pk_fp8_f32(f[0],  f[1],  w0, false);
  w0 = __builtin_amdgcn_cvt_pk_fp8_f32(f[2],  f[3],  w0, true);
  w1 = __builtin_amdgcn_cvt_pk_fp8_f32(f[4],  f[5],  w1, false);
  w1 = __builtin_amdgcn_cvt_pk_fp8_f32(f[6],  f[7],  w1, true);
  w2 = __builtin_amdgcn_cvt_pk_fp8_f32(f[8],  f[9],  w2, false);
  w2 = __builtin_amdgcn_cvt_pk_fp8_f32(f[10], f[11], w2, true);
  w3 = __builtin_amdgcn_cvt_pk_fp8_f32(f[12], f[13], w3, false);
  w3 = __builtin_amdgcn_cvt_pk_fp8_f32(f[14], f[15], w3, true);
  w.x = w0; w.y = w1; w.z = w2; w.w = w3;
  *reinterpret_cast<int4*>(dst + (size_t)c * 2048 + h * 1024 + l * 16) = w;
}

// ---------------------------------------------------------------------------
// Fused fp8 GEMM + row/col sum-exp. 8 waves; wave owns 64 rows (2 row32-groups,
// A in regs: 128 VGPR) -> each B-frag feeds 2 MFMAs (Rm=2, halves B-LDS/FLOP).
// Panel = 32 cols x 512 K fp8 (16 KB), double-buffered. One barrier per panel.
// grid = (split 8, rb 32) = 256 blocks = 1/CU.
// ---------------------------------------------------------------------------
__global__ __launch_bounds__(512, 2) void fused_lse_kernel(
    const char* __restrict__ imgF, const char* __restrict__ txtF,
    float* __restrict__ rowpart,   // [8][16384]
    float* __restrict__ colpart) { // [32][16384]
  const int split = blockIdx.x;          // 0..7 : 2048-col slice
  const int rb    = blockIdx.y;          // 0..31: 512-row block
  const int wid = threadIdx.x >> 6;
  const int l   = threadIdx.x & 63;

  __shared__ int4 BsV[2][1024];          // 2 x 16KB B panel (32 cols x 512 K fp8)
  __shared__ float colLDS[2][8][32];
  char* Bsb = reinterpret_cast<char*>(&BsV[0][0]);

  // prologue: stage panel ct=0 into buf 0 (wave stages 2 x 1KB)
  {
    const char* pb = txtF + (size_t)(split * 64) * 16384;
#pragma unroll
    for (int j = 0; j < 2; ++j) {
      int off = (2 * wid + j) * 1024;
      __builtin_amdgcn_global_load_lds(
          (const __attribute__((address_space(1))) unsigned int*)(pb + off + l * 16),
          (__attribute__((address_space(3))) unsigned int*)(Bsb + off), 16, 0, 0);
    }
  }

  // A: 64 rows x 512 K fp8 in registers (2 rg x 8 k64 x 8 VGPR = 128 VGPR)
  const int grp0 = rb * 16 + wid * 2;
  int8v afrag[2][8];
#pragma unroll
  for (int rg = 0; rg < 2; ++rg)
#pragma unroll
    for (int k = 0; k < 8; ++k) {
      const char* ap = imgF + ((size_t)(grp0 + rg) * 8 + k) * 2048 + l * 16;
      FragU u;
      u.q[0] = *reinterpret_cast<const int4*>(ap);
      u.q[1] = *reinterpret_cast<const int4*>(ap + 1024);
      afrag[rg][k] = u.v;
    }
  asm volatile("" ::: "memory");         // pin afrag: forbid sinking loads into loop
  __syncthreads();

  float rowsum0[16], rowsum1[16];
#pragma unroll
  for (int r = 0; r < 16; ++r) { rowsum0[r] = 0.f; rowsum1[r] = 0.f; }

  const int NCT = 64;                    // 32-col panels per block
  for (int ct = 0; ct < NCT; ++ct) {
    const int cur = ct & 1;
    if (ct + 1 < NCT) {                  // stage next panel; hidden under MFMAs
      const char* pb = txtF + (size_t)(split * 64 + ct + 1) * 16384;
      char* db = Bsb + (cur ^ 1) * 16384;
#pragma unroll
      for (int j = 0; j < 2; ++j) {
        int off = (2 * wid + j) * 1024;
        __builtin_amdgcn_global_load_lds(
            (const __attribute__((address_space(1))) unsigned int*)(pb + off + l * 16),
            (__attribute__((address_space(3))) unsigned int*)(db + off), 16, 0, 0);
      }
    }
    f32x16 acc0, acc1;
#pragma unroll
    for (int r = 0; r < 16; ++r) { acc0[r] = 0.f; acc1[r] = 0.f; }
#pragma unroll
    for (int k = 0; k < 8; ++k) {        // one B-frag -> 2 MFMAs (2 row-groups)
      const char* bp = Bsb + cur * 16384 + k * 2048 + l * 16;
      FragU b;
      b.q[0] = *reinterpret_cast<const int4*>(bp);
      b.q[1] = *reinterpret_cast<const int4*>(bp + 1024);
      acc0 = __builtin_amdgcn_mfma_scale_f32_32x32x64_f8f6f4(
          afrag[0][k], b.v, acc0, 0, 0, 0, SCALE1, 0, SCALE1);
      acc1 = __builtin_amdgcn_mfma_scale_f32_32x32x64_f8f6f4(
          afrag[1][k], b.v, acc1, 0, 0, 0, SCALE1, 0, SCALE1);
    }
    // tail: exp feeds row- and col-sums; no max needed (|arg| < ~2.2)
    float colp = 0.f;
#pragma unroll
    for (int r = 0; r < 16; ++r) {
      float e0 = exp2f(acc0[r]);
      float e1 = exp2f(acc1[r]);
      rowsum0[r] += e0; rowsum1[r] += e1;
      colp += e0 + e1;
    }
    colp += __shfl_xor(colp, 32, 64);    // merge row-halves per col
    if (l < 32) colLDS[cur][wid][l] = colp;
    __syncthreads();                     // drains vmcnt (stage) + orders LDS
    if (threadIdx.x < 32) {              // cross-wave col merge + flush
      float s = 0.f;
#pragma unroll
      for (int w = 0; w < 8; ++w) s += colLDS[cur][w][threadIdx.x];
      colpart[(size_t)rb * N_TOT + (size_t)(split * 64 + ct) * 32 + threadIdx.x] = s;
    }
  }

  // row sums: butterfly over 32 col-lanes (deterministic)
#pragma unroll
  for (int r = 0; r < 16; ++r) {
    float s0 = rowsum0[r], s1 = rowsum1[r];
#pragma unroll
    for (int off = 1; off < 32; off <<= 1) {
      s0 += __shfl_xor(s0, off, 64);
      s1 += __shfl_xor(s1, off, 64);
    }
    rowsum0[r] = s0; rowsum1[r] = s1;
  }
  if ((l & 31) == 0) {
    int rbase = rb * 512 + wid * 64 + ((l >> 5) << 2);
#pragma unroll
    for (int r = 0; r < 16; ++r) {
      int rr = (r & 3) + ((r >> 2) << 3);
      rowpart[(size_t)split * N_TOT + rbase + rr] = rowsum0[r];
      rowpart[(size_t)split * N_TOT + rbase + 32 + rr] = rowsum1[r];
    }
  }
}

// exact fp32 diagonal: one wave per row
__global__ __launch_bounds__(256) void diag_kernel(
    const float* __restrict__ img, const float* __restrict__ txt,
    float* __restrict__ diag) {
  int wid = threadIdx.x >> 6, l = threadIdx.x & 63;
  int row = blockIdx.x * 4 + wid;
  const float4* a = reinterpret_cast<const float4*>(img + (size_t)row * DIM) + l * 2;
  const float4* b = reinterpret_cast<const float4*>(txt + (size_t)row * DIM) + l * 2;
  float s = 0.f;
#pragma unroll
  for (int j = 0; j < 2; ++j) {
    float4 x = a[j], y = b[j];
    s += x.x * y.x + x.y * y.y + x.z * y.z + x.w * y.w;
  }
#pragma unroll
  for (int off = 32; off > 0; off >>= 1) s += __shfl_down(s, off, 64);
  if (l == 0) diag[row] = s;
}

// per-column: sum 32 rb partials, take log
__global__ __launch_bounds__(256) void colreduce_kernel(
    const float* __restrict__ colpart, float* __restrict__ colLSE) {
  int col = blockIdx.x * 256 + threadIdx.x;
  float s = 0.f;
#pragma unroll 8
  for (int g = 0; g < 32; ++g) s += colpart[(size_t)g * N_TOT + col];
  colLSE[col] = __logf(s + EPS);
}

// merge row partials, add col LSEs and diagonal, single-block reduce
__global__ __launch_bounds__(256) void final_kernel(
    const float* __restrict__ rowpart, const float* __restrict__ colLSE,
    const float* __restrict__ diag, const float* __restrict__ scale_p,
    float* __restrict__ out) {
  int t = threadIdx.x;
  float sden = 0.f, sdiag = 0.f;
  for (int i = t; i < N_TOT; i += 256) {
    float rs = 0.f;
#pragma unroll
    for (int sp = 0; sp < 8; ++sp) rs += rowpart[(size_t)sp * N_TOT + i];
    sden += __logf(rs + EPS) + colLSE[i];
    sdiag += diag[i];
  }
  __shared__ float rA[256], rB[256];
  rA[t] = sden; rB[t] = sdiag;
  __syncthreads();
  for (int s2 = 128; s2 > 0; s2 >>= 1) {
    if (t < s2) { rA[t] += rA[t + s2]; rB[t] += rB[t + s2]; }
    __syncthreads();
  }
  if (t == 0)
    out[0] = 0.5f * rA[0] / (float)N_TOT - (*scale_p) * rB[0] / (float)N_TOT;
}

extern "C" void kernel_launch(void* const* d_in, const int* in_sizes, int n_in,
                              void* d_out, int out_size, void* d_ws, size_t ws_size,
                              hipStream_t stream) {
  const float* img     = (const float*)d_in[0];
  const float* txt     = (const float*)d_in[1];
  const float* scale_p = (const float*)d_in[2];
  float* out = (float*)d_out;
  char* ws = (char*)d_ws;   // needs ~19.6 MB
  char*  imgF    = ws;
  char*  txtF    = ws + (size_t)8388608;
  float* colpart = (float*)(ws + (size_t)16777216);
  float* rowpart = (float*)(ws + (size_t)18874368);
  float* colLSE  = (float*)(ws + (size_t)19398656);
  float* diag    = (float*)(ws + (size_t)19464192);

  convert_kernel<<<dim3(2048, 2, 1), 256, 0, stream>>>(img, txt, scale_p, imgF, txtF);
  fused_lse_kernel<<<dim3(8, 32, 1), 512, 0, stream>>>(imgF, txtF, rowpart, colpart);
  diag_kernel<<<dim3(4096, 1, 1), 256, 0, stream>>>(img, txt, diag);
  colreduce_kernel<<<dim3(64, 1, 1), 256, 0, stream>>>(colpart, colLSE);
  final_kernel<<<dim3(1, 1, 1), 256, 0, stream>>>(rowpart, colLSE, diag, scale_p, out);
}